// Round 6
// baseline (3656.247 us; speedup 1.0000x reference)
//
#include <hip/hip_runtime.h>

#define SLEN 512
#define BATCH 64
#define HID 256
#define EMB 128
#define NT 18
#define KTOT 384          // 256 (h) + 128 (emb)
#define BQ 8              // batches per group
#define NGROUP 16         // 2 dirs x 8 batch-chunks
#define NSLICE 32         // producer WGs per group
#define FB 8              // batches per feats block
#define POISON 0xFFFFFFFFu  // -qNaN: legit h (bounded sigmoid/tanh products) is never NaN

typedef unsigned int u32;

__device__ __forceinline__ float sigmoidf_(float v) { return 1.0f / (1.0f + expf(-v)); }

// ---------------------------------------------------------------------------
// Persistent bidirectional LSTM. grid = 512 blocks x 256 threads (all
// co-resident: <=17KB LDS, ~90 VGPR -> >=2 blocks/CU capacity).
// group g = blockIdx&15 : dir = g>>3, batch-chunk = g&7 (8 batches).
// slice rk = blockIdx>>4 (0..31): hidden units [8rk,8rk+8) -> 32 gate rows.
// Weights in VGPRs (8-way K-split, 48 floats/thread).
//
// DATA-POLL exchange (no flags, no producer drain):
//   h_hist is poisoned to NaN (0xFFFFFFFF) each launch by hipMemsetAsync.
//   Producer wave0: gates -> relaxed AGENT h stores (write-through) -> done.
//   Consumer: thread tid polls the 8 words it stages (hid=tid, 8 batches,
//   all written by slice rk'=tid>>3) until non-NaN, into registers.
//   SYNC_P after poll: threads tid in [8rk,8rk+8) poll OUR OWN slice, whose
//   h publishes only after our SYNC_B => at SYNC_P all local GEMM reads of
//   vlds/red are done => restaging is WAR-safe.
// ---------------------------------------------------------------------------
__global__ __launch_bounds__(256, 2) void lstm_kernel(
    const int* __restrict__ x, const float* __restrict__ embed,
    const float* __restrict__ Wih_f, const float* __restrict__ Whh_f,
    const float* __restrict__ bih_f, const float* __restrict__ bhh_f,
    const float* __restrict__ Wih_b, const float* __restrict__ Whh_b,
    const float* __restrict__ bih_b, const float* __restrict__ bhh_b,
    const float* __restrict__ h0, const float* __restrict__ c0,
    float* __restrict__ h_hist)
{
  const int g   = blockIdx.x & 15;
  const int rk  = blockIdx.x >> 4;   // 0..31
  const int dir = g >> 3;
  const int b0  = (g & 7) * BQ;
  const int tid = threadIdx.x;
  const int kg  = tid >> 5;          // 0..7  (K-split group, 48 k's each)
  const int r   = tid & 31;          // row within the 32 gate rows
  const int gi  = r >> 3;            // gate index: 0=i 1=f 2=g 3=o
  const int uo  = r & 7;             // unit offset
  const int grow = gi * 256 + rk * 8 + uo;

  const float* Wih = dir ? Wih_b : Wih_f;
  const float* Whh = dir ? Whh_b : Whh_f;
  const float* bih = dir ? bih_b : bih_f;
  const float* bhh = dir ? bhh_b : bhh_f;

  // persistent weight slice: row 'grow', k in [48*kg, 48*kg+48)
  float4 wreg[12];
#pragma unroll
  for (int c = 0; c < 12; ++c) {
    int k0 = kg * 48 + c * 4;
    if (k0 < 256) wreg[c] = *(const float4*)(Whh + (size_t)grow * 256 + k0);
    else          wreg[c] = *(const float4*)(Wih + (size_t)grow * 128 + (k0 - 256));
  }

  __shared__ float vlds[BQ][KTOT];   // 12 KB : v = [h_prev (256) | emb (128)]
  __shared__ float red[4][BQ][33];   // 4.2 KB : cross-wave partial reduction
  __shared__ float cst[BQ][8];       // cell state (persistent)
  __shared__ float bias[32];

  if (tid < 32) bias[tid] = bih[grow] + bhh[grow];
  if (tid < 64) {
    int b = tid >> 3, u = tid & 7;
    cst[b][u] = c0[(size_t)(dir * BATCH + b0 + b) * HID + rk * 8 + u];
  }
  __syncthreads();

  const int b1 = tid >> 5;           // 0..7 (batch for emb staging)
  const int e1 = (tid & 31) * 4;     // 0..124
  const int wv = tid >> 6;           // wave id 0..3

  for (int it = 0; it < SLEN; ++it) {
    const int t = dir ? (SLEN - 1 - it) : it;

    // ---- prefetch x + embed (step-independent; hides under poll) ----
    int xid = x[(b0 + b1) * SLEN + t];
    float4 ev = *(const float4*)(embed + (size_t)xid * EMB + e1);

    // ---- acquire previous h: poll the 8 words this thread stages ----
    u32 hw[BQ];
    if (it == 0) {
      const u32* hs = (const u32*)(h0 + (size_t)(dir * BATCH + b0) * HID);
#pragma unroll
      for (int i = 0; i < BQ; ++i) hw[i] = hs[tid + i * 256];
    } else {
      const int tp = dir ? (t + 1) : (t - 1);
      const u32* hs = (const u32*)(h_hist +
                       ((size_t)(dir * SLEN + tp) * BATCH + b0) * HID);
#pragma unroll
      for (int i = 0; i < BQ; ++i)
        hw[i] = __hip_atomic_load((u32*)(hs + tid + i * 256),
                                  __ATOMIC_RELAXED, __HIP_MEMORY_SCOPE_AGENT);
      int sp = 0;
      while (true) {
        bool bad = false;
#pragma unroll
        for (int i = 0; i < BQ; ++i) bad |= (hw[i] == POISON);
        if (!bad || ++sp > (1 << 14)) break;
        __builtin_amdgcn_s_sleep(2);
#pragma unroll
        for (int i = 0; i < BQ; ++i)
          if (hw[i] == POISON)
            hw[i] = __hip_atomic_load((u32*)(hs + tid + i * 256),
                                      __ATOMIC_RELAXED, __HIP_MEMORY_SCOPE_AGENT);
      }
    }
    __syncthreads();                                   // SYNC_P (WAR-safe point)

    // ---- stage into LDS ----
    *(float4*)&vlds[b1][256 + e1] = ev;
#pragma unroll
    for (int i = 0; i < BQ; ++i) *(u32*)&vlds[i][tid] = hw[i];
    __syncthreads();                                   // SYNC_A

    // ---- K-split GEMM: acc[b] over this thread's 48 k's ----
    float acc[BQ];
#pragma unroll
    for (int b = 0; b < BQ; ++b) acc[b] = 0.0f;
    const int kb = kg * 48;
#pragma unroll
    for (int c = 0; c < 12; ++c) {
      float4 w4 = wreg[c];
#pragma unroll
      for (int q = 0; q < BQ; ++q) {
        float4 v4 = *(const float4*)&vlds[q][kb + c * 4];
        float a = acc[q];
        a = fmaf(w4.x, v4.x, a);
        a = fmaf(w4.y, v4.y, a);
        a = fmaf(w4.z, v4.z, a);
        a = fmaf(w4.w, v4.w, a);
        acc[q] = a;
      }
    }

    // ---- reduce 8 K-partials: in-wave pair, then 4 waves via LDS ----
#pragma unroll
    for (int b = 0; b < BQ; ++b) acc[b] += __shfl_xor(acc[b], 32);
    if ((tid & 32) == 0) {
#pragma unroll
      for (int b = 0; b < BQ; ++b) red[wv][b][r] = acc[b];
    }
    __syncthreads();                                   // SYNC_B

    // ---- gates + state update + h publish (wave0 only; no drain/flag) ----
    if (tid < 64) {
      int b = tid >> 3, u = tid & 7;
      float gs[4];
#pragma unroll
      for (int gg = 0; gg < 4; ++gg) {
        int rr = gg * 8 + u;
        float s = bias[rr];
#pragma unroll
        for (int w = 0; w < 4; ++w) s += red[w][b][rr];
        gs[gg] = s;
      }
      float ig = sigmoidf_(gs[0]);
      float fg = sigmoidf_(gs[1]);
      float gv = tanhf(gs[2]);
      float og = sigmoidf_(gs[3]);
      float cv = fg * cst[b][u] + ig * gv;
      cst[b][u] = cv;
      float hv = og * tanhf(cv);
      __hip_atomic_store(h_hist + ((size_t)(dir * SLEN + t) * BATCH + (b0 + b)) * HID
                           + rk * 8 + u,
                         hv, __ATOMIC_RELAXED, __HIP_MEMORY_SCOPE_AGENT);
    }
    // no barrier here: next-step SYNC_P provides the WAR guarantee.
  }
}

// ---------------------------------------------------------------------------
// feats[s][b][tag] = [hf|hb] . Wc[tag] + bc[tag]
// grid = 512*8 blocks (s, 8-batch chunk), 256 threads. LDS ~54KB.
// ---------------------------------------------------------------------------
__global__ __launch_bounds__(256) void feats_kernel(
    const float* __restrict__ h_hist, const float* __restrict__ Wc,
    const float* __restrict__ bc, float* __restrict__ feats)
{
  const int s   = blockIdx.x >> 3;
  const int b0  = (blockIdx.x & 7) * FB;
  const int tid = threadIdx.x;
  __shared__ float wc[NT * 516];    // 37.2 KB
  __shared__ float hl[FB * 516];    // 16.5 KB
  __shared__ float bcl[NT];
  if (tid < NT) bcl[tid] = bc[tid];
  for (int f = tid * 4; f < NT * 512; f += 1024) {
    float4 v = *(const float4*)(Wc + f);
    *(float4*)&wc[(f >> 9) * 516 + (f & 511)] = v;
  }
  {
    const float* src0 = h_hist + ((size_t)s * BATCH + b0) * HID;
    const float* src1 = h_hist + ((size_t)(SLEN + s) * BATCH + b0) * HID;
    for (int f = tid * 4; f < FB * 256; f += 1024) {
      int b = f >> 8, j = f & 255;
      *(float4*)&hl[b * 516 + j]       = *(const float4*)(src0 + f);
      *(float4*)&hl[b * 516 + 256 + j] = *(const float4*)(src1 + f);
    }
  }
  __syncthreads();
  if (tid < FB * NT) {
    int b = tid / NT, tag = tid - b * NT;
    float a = bcl[tag];
    const float* hp = &hl[b * 516];
    const float* wp = &wc[tag * 516];
#pragma unroll 8
    for (int k = 0; k < 512; k += 4) {
      float4 h4 = *(const float4*)(hp + k);
      float4 w4 = *(const float4*)(wp + k);
      a = fmaf(h4.x, w4.x, a); a = fmaf(h4.y, w4.y, a);
      a = fmaf(h4.z, w4.z, a); a = fmaf(h4.w, w4.w, a);
    }
    feats[((size_t)s * BATCH + b0 + b) * NT + tag] = a;
  }
}

// ---------------------------------------------------------------------------
// Viterbi + backtrace, one block per batch, 64 threads (lanes 0..17 active).
// Replicates reference exactly, including add order:
//   cur = (feats[to] + trans[from][to]) + partition[from];  new_p = max(cur)
// strict > keeps the FIRST max (matches jnp.argmax). Masked bp=0, snapshot at
// t=len-1, back[len-1]=pointer overwrite, decode[S-1]=pointer.
// ---------------------------------------------------------------------------
__global__ __launch_bounds__(64) void viterbi_kernel(
    const float* __restrict__ feats, const int* __restrict__ mask,
    const float* __restrict__ trans, float* __restrict__ out)
{
  const int b = blockIdx.x;
  const int lane = threadIdx.x;
  __shared__ float tr[NT][NT + 1];
  __shared__ float part[2][NT + 2];
  __shared__ float lastp[NT + 2];
  __shared__ unsigned char bp[SLEN][20];
  __shared__ int len_s;

  for (int f = lane; f < NT * NT; f += 64) tr[f / NT][f % NT] = trans[f];
  int m = 0;
#pragma unroll
  for (int i = 0; i < 8; ++i) m += mask[b * SLEN + lane * 8 + i];
  for (int off = 32; off; off >>= 1) m += __shfl_down(m, off);
  if (lane == 0) len_s = m;
  __syncthreads();
  const int len = len_s;

  if (lane < NT) part[0][lane] = feats[(size_t)b * NT + lane] + tr[16][lane];  // START=16
  __syncthreads();

  int cur = 0;
  float fnext = (lane < NT) ? feats[((size_t)BATCH + b) * NT + lane] : 0.0f;
  int   mnext = mask[b * SLEN + 1];
  for (int t = 1; t < SLEN; ++t) {
    float fcur = fnext; int mcur = mnext;
    if (t < SLEN - 1) {
      fnext = (lane < NT) ? feats[((size_t)(t + 1) * BATCH + b) * NT + lane] : 0.0f;
      mnext = mask[b * SLEN + t + 1];
    }
    if (lane < NT) {
      float best = -3.0e38f; int bf = 0;
#pragma unroll
      for (int from = 0; from < NT; ++from) {
        float v = (fcur + tr[from][lane]) + part[cur][from];  // exact ref order
        if (v > best) { best = v; bf = from; }
      }
      part[cur ^ 1][lane] = best;          // new_p includes feats (ref semantics)
      bp[t][lane] = mcur ? (unsigned char)bf : (unsigned char)0;
      if (t == len - 1) lastp[lane] = best;
    }
    cur ^= 1;
    __syncthreads();
  }

  if (lane == 0) {
    float best = -3.0e38f; int bf = 0;
    for (int from = 0; from < NT; ++from) {
      float v = lastp[from] + tr[from][17];      // END=17
      if (v > best) { best = v; bf = from; }
    }
    out[b] = best;                                // path_score
    int ptr = bf;
    out[BATCH + (size_t)b * SLEN + (SLEN - 1)] = (float)ptr;
    for (int i = SLEN - 2; i >= 0; --i) {
      int nw = (i == len - 1) ? bf : (int)bp[i + 1][ptr];
      out[BATCH + (size_t)b * SLEN + i] = (float)nw;
      ptr = nw;
    }
  }
}

// ---------------------------------------------------------------------------
extern "C" void kernel_launch(void* const* d_in, const int* in_sizes, int n_in,
                              void* d_out, int out_size, void* d_ws, size_t ws_size,
                              hipStream_t stream) {
  const int*   x      = (const int*)  d_in[0];
  const int*   mask   = (const int*)  d_in[1];
  const float* embed  = (const float*)d_in[2];
  const float* Wih_f  = (const float*)d_in[3];
  const float* Whh_f  = (const float*)d_in[4];
  const float* bih_f  = (const float*)d_in[5];
  const float* bhh_f  = (const float*)d_in[6];
  const float* Wih_b  = (const float*)d_in[7];
  const float* Whh_b  = (const float*)d_in[8];
  const float* bih_b  = (const float*)d_in[9];
  const float* bhh_b  = (const float*)d_in[10];
  const float* Wc     = (const float*)d_in[11];
  const float* bc     = (const float*)d_in[12];
  const float* trans  = (const float*)d_in[13];
  const float* h0     = (const float*)d_in[14];
  const float* c0     = (const float*)d_in[15];
  float* out = (float*)d_out;

  // ws layout: h_hist @0 (64MB, NaN-poisoned each launch); feats @64MB.
  char* ws = (char*)d_ws;
  float* h_hist = (float*)ws;                                 // 64 MB
  float* feats  = (float*)(ws + (size_t)67108864);            // 2.25 MB

  const size_t hbytes = (size_t)2 * SLEN * BATCH * HID * sizeof(float);
  hipMemsetAsync(h_hist, 0xFF, hbytes, stream);   // poison = NaN
  lstm_kernel<<<512, 256, 0, stream>>>(x, embed, Wih_f, Whh_f, bih_f, bhh_f,
                                       Wih_b, Whh_b, bih_b, bhh_b, h0, c0,
                                       h_hist);
  feats_kernel<<<SLEN * 8, 256, 0, stream>>>(h_hist, Wc, bc, feats);
  viterbi_kernel<<<BATCH, 64, 0, stream>>>(feats, mask, trans, out);
}

// Round 7
// 2973.189 us; speedup vs baseline: 1.2297x; 1.2297x over previous
//
#include <hip/hip_runtime.h>

#define SLEN 512
#define BATCH 64
#define HID 256
#define EMB 128
#define NT 18
#define BQ 8              // batches per group
#define NGROUP 16         // 2 dirs x 8 batch-chunks
#define NSLICE 32         // producer WGs per group
#define FB 8              // batches per feats block

typedef unsigned int u32;

__device__ __forceinline__ float sigmoidf_(float v) { return 1.0f / (1.0f + expf(-v)); }

// ---------------------------------------------------------------------------
// Persistent bidirectional LSTM. grid = 512 blocks x 256 threads (~21KB LDS,
// 2 blocks/CU). group g = blockIdx&15 : dir = g>>3, chunk = g&7 (8 batches).
// slice rk = blockIdx>>4 (0..31): hidden units [8rk,8rk+8) -> 32 gate rows.
// Per-thread K-slice: 32 h-k's [32kg,32kg+32) + 16 emb-k's [16kg,16kg+16).
//
// Flag protocol (round-4, best known) with pipelined legs:
//   end of step t  : wave0 computes gates, ISSUES h stores (relaxed AGENT).
//   top of step t+1: all waves run emb-GEMM(t+1) from LDS double buffer
//                    (hides producer drain + flag latency);
//                    wave0: vmcnt(0) -> flag(t) -> spin LDS ready;
//                    wave1: poll 32 flags (1 line) -> ready = t+1;
//                    waves 2,3: spin ready.
//   then           : burst-fetch h(t) (bypass loads, once), stage, SYNC_A,
//                    h-GEMM (+ issue embed(t+3)/x(t+4) prefetch), reduce,
//                    SYNC_B, gates...
// ---------------------------------------------------------------------------
__global__ __launch_bounds__(256, 2) void lstm_kernel(
    const int* __restrict__ x, const float* __restrict__ embed,
    const float* __restrict__ Wih_f, const float* __restrict__ Whh_f,
    const float* __restrict__ bih_f, const float* __restrict__ bhh_f,
    const float* __restrict__ Wih_b, const float* __restrict__ Whh_b,
    const float* __restrict__ bih_b, const float* __restrict__ bhh_b,
    const float* __restrict__ h0, const float* __restrict__ c0,
    float* __restrict__ h_hist, u32* __restrict__ flags)
{
  const int g   = blockIdx.x & 15;
  const int rk  = blockIdx.x >> 4;   // 0..31
  const int dir = g >> 3;
  const int b0  = (g & 7) * BQ;
  const int tid = threadIdx.x;
  const int kg  = tid >> 5;          // 0..7 (K-split group)
  const int r   = tid & 31;          // row within the 32 gate rows
  const int gi  = r >> 3;            // gate: 0=i 1=f 2=g 3=o
  const int uo  = r & 7;
  const int grow = gi * 256 + rk * 8 + uo;
  const int wv  = tid >> 6;          // wave id 0..3

  const float* Wih = dir ? Wih_b : Wih_f;
  const float* Whh = dir ? Whh_b : Whh_f;
  const float* bih = dir ? bih_b : bih_f;
  const float* bhh = dir ? bhh_b : bhh_f;

  // weights: c 0..7 -> Whh[grow][32kg+4c] ; c 8..11 -> Wih[grow][16kg+4(c-8)]
  float4 wreg[12];
#pragma unroll
  for (int c = 0; c < 8; ++c)
    wreg[c] = *(const float4*)(Whh + (size_t)grow * 256 + kg * 32 + c * 4);
#pragma unroll
  for (int c = 8; c < 12; ++c)
    wreg[c] = *(const float4*)(Wih + (size_t)grow * 128 + kg * 16 + (c - 8) * 4);

  __shared__ float vh[BQ][HID];        // 8 KB   h(t-1) staging
  __shared__ float vemb[2][BQ][EMB];   // 8 KB   emb double buffer
  __shared__ float red[4][BQ][33];     // 4.2 KB cross-wave partials
  __shared__ float cst[BQ][8];         // cell state
  __shared__ float bias[32];
  __shared__ u32   ready;

  if (tid < 32) bias[tid] = bih[grow] + bhh[grow];
  if (tid < 64) {
    int b = tid >> 3, u = tid & 7;
    cst[b][u] = c0[(size_t)(dir * BATCH + b0 + b) * HID + rk * 8 + u];
  }
  if (tid == 0) ready = 0;

  const int b1 = tid >> 5;           // batch for emb staging
  const int e1 = (tid & 31) * 4;     // emb element offset

  // ---- prologue: stage emb(0); put emb(1) gather + x(2) in flight ----
  {
    int xid0 = x[(b0 + b1) * SLEN + (dir ? SLEN - 1 : 0)];
    float4 e0 = *(const float4*)(embed + (size_t)xid0 * EMB + e1);
    *(float4*)&vemb[0][b1][e1] = e0;
  }
  int xv;                            // x index for step it+2 (in flight)
  float4 ev;                         // embed data for step it+1 (in flight)
  {
    int xid1 = x[(b0 + b1) * SLEN + (dir ? SLEN - 2 : 1)];
    ev = *(const float4*)(embed + (size_t)xid1 * EMB + e1);
    xv = x[(b0 + b1) * SLEN + (dir ? SLEN - 3 : 2)];
  }
  __syncthreads();

  for (int it = 0; it < SLEN; ++it) {
    const int t = dir ? (SLEN - 1 - it) : it;

    // ---- 1. emb-GEMM from vemb[it&1] (hides producer drain / flag legs) ---
    float acc[BQ];
#pragma unroll
    for (int b = 0; b < BQ; ++b) acc[b] = 0.0f;
    {
      const int keb = kg * 16;
#pragma unroll
      for (int c = 0; c < 4; ++c) {
        float4 w4 = wreg[8 + c];
#pragma unroll
        for (int q = 0; q < BQ; ++q) {
          float4 v4 = *(const float4*)&vemb[it & 1][q][keb + c * 4];
          float a = acc[q];
          a = fmaf(w4.x, v4.x, a); a = fmaf(w4.y, v4.y, a);
          a = fmaf(w4.z, v4.z, a); a = fmaf(w4.w, v4.w, a);
          acc[q] = a;
        }
      }
    }

    // ---- 2. publish flag (wave0) / poll (wave1) / spin (2,3) -------------
    if (it > 0) {
      if (wv == 0) {
        asm volatile("s_waitcnt vmcnt(0)" ::: "memory");   // h(t-1) committed
        if (tid == 0)
          __hip_atomic_store(flags + ((size_t)g * SLEN + (it - 1)) * NSLICE + rk,
                             1u, __ATOMIC_RELAXED, __HIP_MEMORY_SCOPE_AGENT);
        int sp = 0;
        while (*((volatile u32*)&ready) < (u32)it && ++sp < (1 << 20))
          __builtin_amdgcn_s_sleep(1);
      } else if (wv == 1) {
        const u32* fl = flags + ((size_t)g * SLEN + (it - 1)) * NSLICE + (tid & 31);
        int sp = 0;
        u32 v = __hip_atomic_load((u32*)fl, __ATOMIC_RELAXED, __HIP_MEMORY_SCOPE_AGENT);
        while (!__all(v != 0) && ++sp < (1 << 14)) {
          __builtin_amdgcn_s_sleep(1);
          v = __hip_atomic_load((u32*)fl, __ATOMIC_RELAXED, __HIP_MEMORY_SCOPE_AGENT);
        }
        if (tid == 64) *((volatile u32*)&ready) = (u32)it;
      } else {
        int sp = 0;
        while (*((volatile u32*)&ready) < (u32)it && ++sp < (1 << 20))
          __builtin_amdgcn_s_sleep(1);
      }
    }
    asm volatile("" ::: "memory");

    // ---- 3. burst-fetch h(t-1) (bypass loads, exactly once) --------------
    u32 hw[BQ];
    if (it == 0) {
      const u32* hs = (const u32*)(h0 + (size_t)(dir * BATCH + b0) * HID);
#pragma unroll
      for (int i = 0; i < BQ; ++i) hw[i] = hs[tid + i * 256];
    } else {
      const int tp = dir ? (t + 1) : (t - 1);
      const u32* hs = (const u32*)(h_hist +
                       ((size_t)(dir * SLEN + tp) * BATCH + b0) * HID);
#pragma unroll
      for (int i = 0; i < BQ; ++i)
        hw[i] = __hip_atomic_load((u32*)(hs + tid + i * 256),
                                  __ATOMIC_RELAXED, __HIP_MEMORY_SCOPE_AGENT);
    }

    // ---- 4. stage h + next emb (register data, no stall) -----------------
#pragma unroll
    for (int i = 0; i < BQ; ++i) *(u32*)&vh[i][tid] = hw[i];
    *(float4*)&vemb[(it + 1) & 1][b1][e1] = ev;
    __syncthreads();                                   // SYNC_A

    // ---- 5. h-GEMM + issue deep prefetch (emb(t+2), x(t+3)) --------------
    {
      int s2 = it + 2 < SLEN ? it + 2 : SLEN - 1;
      int s3 = it + 3 < SLEN ? it + 3 : SLEN - 1;
      int t2 = dir ? (SLEN - 1 - s2) : s2;
      int t3 = dir ? (SLEN - 1 - s3) : s3;
      ev = *(const float4*)(embed + (size_t)xv * EMB + e1);  // emb for step it+2
      xv = x[(b0 + b1) * SLEN + t3];                         // x for step it+3
      (void)t2;
    }
    {
      const int khb = kg * 32;
#pragma unroll
      for (int c = 0; c < 8; ++c) {
        float4 w4 = wreg[c];
#pragma unroll
        for (int q = 0; q < BQ; ++q) {
          float4 v4 = *(const float4*)&vh[q][khb + c * 4];
          float a = acc[q];
          a = fmaf(w4.x, v4.x, a); a = fmaf(w4.y, v4.y, a);
          a = fmaf(w4.z, v4.z, a); a = fmaf(w4.w, v4.w, a);
          acc[q] = a;
        }
      }
    }

    // ---- 6. reduce 8 K-partials: shfl pair + 4 waves via LDS -------------
#pragma unroll
    for (int b = 0; b < BQ; ++b) acc[b] += __shfl_xor(acc[b], 32);
    if ((tid & 32) == 0) {
#pragma unroll
      for (int b = 0; b < BQ; ++b) red[wv][b][r] = acc[b];
    }
    __syncthreads();                                   // SYNC_B

    // ---- 7. gates + state + h stores (wave0; drain deferred to next top) -
    if (tid < 64) {
      int b = tid >> 3, u = tid & 7;
      float gs[4];
#pragma unroll
      for (int gg = 0; gg < 4; ++gg) {
        int rr = gg * 8 + u;
        float s = bias[rr];
#pragma unroll
        for (int w = 0; w < 4; ++w) s += red[w][b][rr];
        gs[gg] = s;
      }
      float ig = sigmoidf_(gs[0]);
      float fg = sigmoidf_(gs[1]);
      float gv = tanhf(gs[2]);
      float og = sigmoidf_(gs[3]);
      float cv = fg * cst[b][u] + ig * gv;
      cst[b][u] = cv;
      float hv = og * tanhf(cv);
      __hip_atomic_store(h_hist + ((size_t)(dir * SLEN + t) * BATCH + (b0 + b)) * HID
                           + rk * 8 + u,
                         hv, __ATOMIC_RELAXED, __HIP_MEMORY_SCOPE_AGENT);
    }
    // no barrier: next-iter SYNC_A provides WAR safety (all waves passed
    // SYNC_B before any step-t+1 LDS restaging).
  }
}

// ---------------------------------------------------------------------------
// feats[s][b][tag] = [hf|hb] . Wc[tag] + bc[tag]
// grid = 512*8 blocks (s, 8-batch chunk), 256 threads. LDS ~54KB.
// ---------------------------------------------------------------------------
__global__ __launch_bounds__(256) void feats_kernel(
    const float* __restrict__ h_hist, const float* __restrict__ Wc,
    const float* __restrict__ bc, float* __restrict__ feats)
{
  const int s   = blockIdx.x >> 3;
  const int b0  = (blockIdx.x & 7) * FB;
  const int tid = threadIdx.x;
  __shared__ float wc[NT * 516];    // 37.2 KB
  __shared__ float hl[FB * 516];    // 16.5 KB
  __shared__ float bcl[NT];
  if (tid < NT) bcl[tid] = bc[tid];
  for (int f = tid * 4; f < NT * 512; f += 1024) {
    float4 v = *(const float4*)(Wc + f);
    *(float4*)&wc[(f >> 9) * 516 + (f & 511)] = v;
  }
  {
    const float* src0 = h_hist + ((size_t)s * BATCH + b0) * HID;
    const float* src1 = h_hist + ((size_t)(SLEN + s) * BATCH + b0) * HID;
    for (int f = tid * 4; f < FB * 256; f += 1024) {
      int b = f >> 8, j = f & 255;
      *(float4*)&hl[b * 516 + j]       = *(const float4*)(src0 + f);
      *(float4*)&hl[b * 516 + 256 + j] = *(const float4*)(src1 + f);
    }
  }
  __syncthreads();
  if (tid < FB * NT) {
    int b = tid / NT, tag = tid - b * NT;
    float a = bcl[tag];
    const float* hp = &hl[b * 516];
    const float* wp = &wc[tag * 516];
#pragma unroll 8
    for (int k = 0; k < 512; k += 4) {
      float4 h4 = *(const float4*)(hp + k);
      float4 w4 = *(const float4*)(wp + k);
      a = fmaf(h4.x, w4.x, a); a = fmaf(h4.y, w4.y, a);
      a = fmaf(h4.z, w4.z, a); a = fmaf(h4.w, w4.w, a);
    }
    feats[((size_t)s * BATCH + b0 + b) * NT + tag] = a;
  }
}

// ---------------------------------------------------------------------------
// Viterbi + backtrace, one block per batch, 64 threads (lanes 0..17 active).
// Replicates reference exactly, including add order:
//   cur = (feats[to] + trans[from][to]) + partition[from];  new_p = max(cur)
// strict > keeps the FIRST max (matches jnp.argmax). Masked bp=0, snapshot at
// t=len-1, back[len-1]=pointer overwrite, decode[S-1]=pointer.
// ---------------------------------------------------------------------------
__global__ __launch_bounds__(64) void viterbi_kernel(
    const float* __restrict__ feats, const int* __restrict__ mask,
    const float* __restrict__ trans, float* __restrict__ out)
{
  const int b = blockIdx.x;
  const int lane = threadIdx.x;
  __shared__ float tr[NT][NT + 1];
  __shared__ float part[2][NT + 2];
  __shared__ float lastp[NT + 2];
  __shared__ unsigned char bp[SLEN][20];
  __shared__ int len_s;

  for (int f = lane; f < NT * NT; f += 64) tr[f / NT][f % NT] = trans[f];
  int m = 0;
#pragma unroll
  for (int i = 0; i < 8; ++i) m += mask[b * SLEN + lane * 8 + i];
  for (int off = 32; off; off >>= 1) m += __shfl_down(m, off);
  if (lane == 0) len_s = m;
  __syncthreads();
  const int len = len_s;

  if (lane < NT) part[0][lane] = feats[(size_t)b * NT + lane] + tr[16][lane];  // START=16
  __syncthreads();

  int cur = 0;
  float fnext = (lane < NT) ? feats[((size_t)BATCH + b) * NT + lane] : 0.0f;
  int   mnext = mask[b * SLEN + 1];
  for (int t = 1; t < SLEN; ++t) {
    float fcur = fnext; int mcur = mnext;
    if (t < SLEN - 1) {
      fnext = (lane < NT) ? feats[((size_t)(t + 1) * BATCH + b) * NT + lane] : 0.0f;
      mnext = mask[b * SLEN + t + 1];
    }
    if (lane < NT) {
      float best = -3.0e38f; int bf = 0;
#pragma unroll
      for (int from = 0; from < NT; ++from) {
        float v = (fcur + tr[from][lane]) + part[cur][from];  // exact ref order
        if (v > best) { best = v; bf = from; }
      }
      part[cur ^ 1][lane] = best;          // new_p includes feats (ref semantics)
      bp[t][lane] = mcur ? (unsigned char)bf : (unsigned char)0;
      if (t == len - 1) lastp[lane] = best;
    }
    cur ^= 1;
    __syncthreads();
  }

  if (lane == 0) {
    float best = -3.0e38f; int bf = 0;
    for (int from = 0; from < NT; ++from) {
      float v = lastp[from] + tr[from][17];      // END=17
      if (v > best) { best = v; bf = from; }
    }
    out[b] = best;                                // path_score
    int ptr = bf;
    out[BATCH + (size_t)b * SLEN + (SLEN - 1)] = (float)ptr;
    for (int i = SLEN - 2; i >= 0; --i) {
      int nw = (i == len - 1) ? bf : (int)bp[i + 1][ptr];
      out[BATCH + (size_t)b * SLEN + i] = (float)nw;
      ptr = nw;
    }
  }
}

// ---------------------------------------------------------------------------
extern "C" void kernel_launch(void* const* d_in, const int* in_sizes, int n_in,
                              void* d_out, int out_size, void* d_ws, size_t ws_size,
                              hipStream_t stream) {
  const int*   x      = (const int*)  d_in[0];
  const int*   mask   = (const int*)  d_in[1];
  const float* embed  = (const float*)d_in[2];
  const float* Wih_f  = (const float*)d_in[3];
  const float* Whh_f  = (const float*)d_in[4];
  const float* bih_f  = (const float*)d_in[5];
  const float* bhh_f  = (const float*)d_in[6];
  const float* Wih_b  = (const float*)d_in[7];
  const float* Whh_b  = (const float*)d_in[8];
  const float* bih_b  = (const float*)d_in[9];
  const float* bhh_b  = (const float*)d_in[10];
  const float* Wc     = (const float*)d_in[11];
  const float* bc     = (const float*)d_in[12];
  const float* trans  = (const float*)d_in[13];
  const float* h0     = (const float*)d_in[14];
  const float* c0     = (const float*)d_in[15];
  float* out = (float*)d_out;

  // ws layout: h_hist @0 (64MB); flags and feats SHARE ws+64MB (disjoint in
  // time: flags used only during lstm, feats written only after lstm; flags
  // re-zeroed each launch -> graph-replay deterministic).
  char* ws = (char*)d_ws;
  float* h_hist = (float*)ws;                                 // 64 MB
  u32*   flags  = (u32*)(ws + (size_t)67108864);              // 1 MB
  float* feats  = (float*)(ws + (size_t)67108864);            // 2.25 MB (aliases flags)

  hipMemsetAsync(flags, 0, (size_t)NGROUP * SLEN * NSLICE * sizeof(u32), stream);
  lstm_kernel<<<512, 256, 0, stream>>>(x, embed, Wih_f, Whh_f, bih_f, bhh_f,
                                       Wih_b, Whh_b, bih_b, bhh_b, h0, c0,
                                       h_hist, flags);
  feats_kernel<<<SLEN * 8, 256, 0, stream>>>(h_hist, Wc, bc, feats);
  viterbi_kernel<<<BATCH, 64, 0, stream>>>(feats, mask, trans, out);
}